// Round 13
// baseline (152.613 us; speedup 1.0000x reference)
//
#include <hip/hip_runtime.h>
#include <hip/hip_bf16.h>
#include <math.h>

#define H_DIM 4096
#define N_EXP 64
#define N_TOK 16384
#define BM    32
#define KB    64
#define NCHUNK (H_DIM / KB)   // 64
#define MARGIN 1e-3f
#define SLOT_BYTES 24576      // xh 4KB @0 | xm 4KB @4096 | W 16KB @8192

typedef __attribute__((ext_vector_type(8))) short short8v;
typedef __attribute__((ext_vector_type(4))) float float4v;

__device__ __forceinline__ unsigned short bf16_rn(float f) {
    unsigned u = __builtin_bit_cast(unsigned, f);
    u += 0x7FFFu + ((u >> 16) & 1u);
    return (unsigned short)(u >> 16);
}
__device__ __forceinline__ float bf16_hi_f32(unsigned u) {
    return __builtin_bit_cast(float, u & 0xFFFF0000u);
}
__device__ __forceinline__ void gload_lds16(const void* g, void* l) {
    __builtin_amdgcn_global_load_lds(
        (const __attribute__((address_space(1))) unsigned int*)g,
        (__attribute__((address_space(3))) unsigned int*)l, 16, 0, 0);
}

// ---- W split (2-term): w = wh(trunc) + wm(rn); zero the fixup counter ----
__global__ __launch_bounds__(256)
void wconvert_kernel(const float* __restrict__ W,
                     unsigned short* __restrict__ wh,
                     unsigned short* __restrict__ wm,
                     int* __restrict__ counter) {
    int i = blockIdx.x * 256 + threadIdx.x;
    if (i == 0) *counter = 0;
    float w = W[i];
    unsigned u = __builtin_bit_cast(unsigned, w);
    wh[i] = (unsigned short)(u >> 16);
    wm[i] = bf16_rn(w - bf16_hi_f32(u));
}

// ---- logits: 4-term split-bf16 MFMA; 3-slot ring, ONE barrier/chunk,
//      x split at staging (reg->bf16->LDS), W via gload_lds; fused topk ----
__global__ __launch_bounds__(256, 2)
void router_mfma_kernel(const float* __restrict__ x,
                        const unsigned short* __restrict__ wh,
                        const unsigned short* __restrict__ wm,
                        const float* __restrict__ bias,
                        float* __restrict__ logits,
                        float* __restrict__ wout,
                        float* __restrict__ iout,
                        int* __restrict__ counter,
                        int* __restrict__ list) {
    __shared__ char smem[3 * SLOT_BYTES];   // 72 KB
    float* olds = (float*)smem;             // [32][66] overlay, used after K-loop

    const int tid  = threadIdx.x;
    const int lane = tid & 63;
    const int wid  = __builtin_amdgcn_readfirstlane(tid >> 6);
    const int tok0 = blockIdx.x * BM;

    const int q    = lane >> 4;        // 0..3
    const int e15  = lane & 15;
    const int mt   = wid & 1;          // wave's m-tile (16 tokens)
    const int eg   = wid >> 1;         // wave's expert half (32 experts)
    const int arow = mt * 16 + e15;    // token row in x tile
    const int er0  = eg * 32 + e15;
    const int er1  = eg * 32 + 16 + e15;

    // staging coords: thread owns 8 consecutive k of one row
    const int srow = tid >> 3;         // 0..31
    const int skg  = tid & 7;          // 0..7
    const float* xsrc = x + (size_t)(tok0 + srow) * H_DIM + skg * 8;
    const int xoff = (skg * 32 + srow) * 16;   // [u][row] 16B units

    float4v acc0 = {0.f, 0.f, 0.f, 0.f};
    float4v acc1 = {0.f, 0.f, 0.f, 0.f};

    auto issue_x = [&](float4& g0, float4& g1, int c) {
        const float* s = xsrc + c * KB;
        g0 = *(const float4*)(s);
        g1 = *(const float4*)(s + 4);
    };
    auto write_x = [&](float4 g0, float4 g1, int slot) {
        float f[8] = {g0.x, g0.y, g0.z, g0.w, g1.x, g1.y, g1.z, g1.w};
        short8v xh8, xm8;
#pragma unroll
        for (int j = 0; j < 8; ++j) {
            unsigned u = __builtin_bit_cast(unsigned, f[j]);
            xh8[j] = (short)(u >> 16);
            xm8[j] = (short)bf16_rn(f[j] - bf16_hi_f32(u));
        }
        char* base = smem + slot * SLOT_BYTES;
        *(short8v*)(base + xoff)        = xh8;   // ds_write_b128
        *(short8v*)(base + 4096 + xoff) = xm8;
    };
    auto issue_w = [&](int slot, int c) {
        const int kc = c * KB;
        char* wdst = smem + slot * SLOT_BYTES + 8192;
#pragma unroll
        for (int j = 0; j < 4; ++j) {
            int idx = j * 256 + tid;
            int s = idx >> 9, e = (idx >> 3) & 63, u = idx & 7;
            int us = u ^ (e & 7);
            const unsigned short* wsrc = s ? wm : wh;
            const unsigned short* src  = wsrc + (size_t)e * H_DIM + kc + us * 8;
            gload_lds16(src, wdst + (size_t)(j * 256 + wid * 64) * 16);
        }
    };
    auto compute = [&](int slot) {
        const char* xc = smem + slot * SLOT_BYTES;
        const char* wc = xc + 8192;
#pragma unroll
        for (int t = 0; t < 2; ++t) {
            int au = ((t * 4 + q) * 32 + arow) * 16;
            short8v ah = *(const short8v*)(xc + au);
            short8v am = *(const short8v*)(xc + 4096 + au);
            int up = (t * 4 + q) ^ (e15 & 7);
            short8v bh0 = *(const short8v*)(wc + (size_t)(er0 * 8 + up) * 16);
            short8v bh1 = *(const short8v*)(wc + (size_t)(er1 * 8 + up) * 16);
            short8v bm0 = *(const short8v*)(wc + 8192 + (size_t)(er0 * 8 + up) * 16);
            short8v bm1 = *(const short8v*)(wc + 8192 + (size_t)(er1 * 8 + up) * 16);

            acc0 = __builtin_amdgcn_mfma_f32_16x16x32_bf16(ah, bh0, acc0, 0, 0, 0);
            acc1 = __builtin_amdgcn_mfma_f32_16x16x32_bf16(ah, bh1, acc1, 0, 0, 0);
            acc0 = __builtin_amdgcn_mfma_f32_16x16x32_bf16(am, bh0, acc0, 0, 0, 0);
            acc1 = __builtin_amdgcn_mfma_f32_16x16x32_bf16(am, bh1, acc1, 0, 0, 0);
            acc0 = __builtin_amdgcn_mfma_f32_16x16x32_bf16(ah, bm0, acc0, 0, 0, 0);
            acc1 = __builtin_amdgcn_mfma_f32_16x16x32_bf16(ah, bm1, acc1, 0, 0, 0);
            acc0 = __builtin_amdgcn_mfma_f32_16x16x32_bf16(am, bm0, acc0, 0, 0, 0);
            acc1 = __builtin_amdgcn_mfma_f32_16x16x32_bf16(am, bm1, acc1, 0, 0, 0);
        }
    };

    float4 xrA0, xrA1, xrB0, xrB1;

    // ---- prologue: chunk 0 staged fully; chunk 1 in flight ----
    issue_x(xrA0, xrA1, 0);
    issue_w(0, 0);
    write_x(xrA0, xrA1, 0);                 // compiler inserts vmcnt for xrA
    issue_x(xrB0, xrB1, 1);
    issue_w(1, 1);
    asm volatile("s_waitcnt vmcnt(6)" ::: "memory");   // W(0) landed

    // ---- main loop: chunks 0..61, one barrier per chunk ----
    for (int c = 0; c < NCHUNK - 2; c += 2) {
        asm volatile("s_waitcnt lgkmcnt(0)" ::: "memory");
        __builtin_amdgcn_s_barrier();
        write_x(xrB0, xrB1, (c + 1) % 3);
        issue_x(xrA0, xrA1, c + 2);
        issue_w((c + 2) % 3, c + 2);
        asm volatile("s_waitcnt vmcnt(6)" ::: "memory");
        compute(c % 3);

        asm volatile("s_waitcnt lgkmcnt(0)" ::: "memory");
        __builtin_amdgcn_s_barrier();
        write_x(xrA0, xrA1, (c + 2) % 3);
        issue_x(xrB0, xrB1, c + 3);
        issue_w((c + 3) % 3, c + 3);
        asm volatile("s_waitcnt vmcnt(6)" ::: "memory");
        compute((c + 1) % 3);
    }
    // ---- peeled chunk 62: write x(63), drain W(63) ----
    asm volatile("s_waitcnt lgkmcnt(0)" ::: "memory");
    __builtin_amdgcn_s_barrier();
    write_x(xrB0, xrB1, (NCHUNK - 1) % 3);   // x63 -> slot 0
    asm volatile("s_waitcnt vmcnt(0)" ::: "memory");
    compute((NCHUNK - 2) % 3);               // slot 2
    // ---- peeled chunk 63 ----
    asm volatile("s_waitcnt lgkmcnt(0)" ::: "memory");
    __builtin_amdgcn_s_barrier();
    compute((NCHUNK - 1) % 3);               // slot 0
    __syncthreads();                         // free slot 0 before olds overlay

    // ---- epilogue: bias, store logits, stage transpose for fused topk ----
    float bv0 = bias[er0], bv1 = bias[er1];
#pragma unroll
    for (int r = 0; r < 4; ++r) {
        int trow = mt * 16 + q * 4 + r;      // C: row=(lane>>4)*4+r, col=lane&15
        float v0 = acc0[r] + bv0;
        float v1 = acc1[r] + bv1;
        logits[(size_t)(tok0 + trow) * N_EXP + er0] = v0;
        logits[(size_t)(tok0 + trow) * N_EXP + er1] = v1;
        olds[trow * 66 + er0] = v0;
        olds[trow * 66 + er1] = v1;
    }
    __syncthreads();

    // ---- fused wave-parallel softmax + top-2 (+ near-tie flag) ----
#pragma unroll
    for (int it = 0; it < 8; ++it) {
        const int nl = wid * 8 + it;
        const int n  = tok0 + nl;
        float l = olds[nl * 66 + lane];

        float v1 = l; int i1 = lane;
#pragma unroll
        for (int off = 32; off >= 1; off >>= 1) {
            float ov = __shfl_xor(v1, off);
            int   oi = __shfl_xor(i1, off);
            if (ov > v1 || (ov == v1 && oi < i1)) { v1 = ov; i1 = oi; }
        }
        float l2 = (lane == i1) ? -INFINITY : l;
        float v2 = l2; int i2 = lane;
#pragma unroll
        for (int off = 32; off >= 1; off >>= 1) {
            float ov = __shfl_xor(v2, off);
            int   oi = __shfl_xor(i2, off);
            if (ov > v2 || (ov == v2 && oi < i2)) { v2 = ov; i2 = oi; }
        }
        float l3 = (lane == i1 || lane == i2) ? -INFINITY : l;
        float v3 = l3;
#pragma unroll
        for (int off = 32; off >= 1; off >>= 1)
            v3 = fmaxf(v3, __shfl_xor(v3, off));

        float Z = expf(l - v1);
#pragma unroll
        for (int off = 32; off >= 1; off >>= 1) Z += __shfl_xor(Z, off);

        if (lane == 0) {
            float p1 = 1.0f / Z;
            float p2 = expf(v2 - v1) / Z;
            float t  = expf(p2 - p1);
            wout[2 * n + 0] = 1.0f / (1.0f + t);
            wout[2 * n + 1] = t / (1.0f + t);
            iout[2 * n + 0] = (float)i1;
            iout[2 * n + 1] = (float)i2;
            if ((v1 - v2 < MARGIN) || (v2 - v3 < MARGIN)) {
                int sidx = atomicAdd(counter, 1);
                list[sidx] = n;
            }
        }
    }
}

// ---- fallback exact-f32 GEMM ----
__global__ __launch_bounds__(256)
void router_logits_f32(const float* __restrict__ x,
                       const float* __restrict__ W,
                       const float* __restrict__ bias,
                       float* __restrict__ logits) {
    __shared__ float4 wlds[32 * 64];
    __shared__ float4 xlds[32][32];
    const int tid = threadIdx.x;
    const int lane = tid & 63;
    const int wid = __builtin_amdgcn_readfirstlane(tid >> 6);
    const int tok0b = blockIdx.x * 32;
    const int trow0 = wid * 8;
    float acc[8];
#pragma unroll
    for (int t = 0; t < 8; ++t) acc[t] = 0.0f;
    for (int kc = 0; kc < H_DIM; kc += 128) {
        __syncthreads();
#pragma unroll
        for (int i = 0; i < 8; ++i) {
            int idx = tid + i * 256;
            int se = idx >> 5, sj = idx & 31;
            float4 v = *(const float4*)(W + (size_t)se * H_DIM + kc + sj * 4);
            wlds[sj * 64 + (se ^ (sj & 7))] = v;
        }
#pragma unroll
        for (int i = 0; i < 4; ++i) {
            int idx = tid + i * 256;
            int row = idx >> 5, col = idx & 31;
            xlds[row][col] = *(const float4*)(x + (size_t)(tok0b + row) * H_DIM + kc + col * 4);
        }
        __syncthreads();
#pragma unroll 4
        for (int jg = 0; jg < 32; ++jg) {
            float4 w = wlds[jg * 64 + (lane ^ (jg & 7))];
#pragma unroll
            for (int t = 0; t < 8; ++t) {
                float4 xv = xlds[trow0 + t][jg];
                acc[t] = fmaf(w.x, xv.x, acc[t]);
                acc[t] = fmaf(w.y, xv.y, acc[t]);
                acc[t] = fmaf(w.z, xv.z, acc[t]);
                acc[t] = fmaf(w.w, xv.w, acc[t]);
            }
        }
    }
    float bv = bias[lane];
#pragma unroll
    for (int t = 0; t < 8; ++t)
        logits[(size_t)(tok0b + trow0 + t) * N_EXP + lane] = acc[t] + bv;
}

// ---- standalone wave-parallel topk (fallback path) ----
__global__ __launch_bounds__(256)
void topk_kernel(const float* __restrict__ logits,
                 float* __restrict__ wout,
                 float* __restrict__ iout) {
    const int lane = threadIdx.x & 63;
    const int wid  = threadIdx.x >> 6;
    const int wg   = blockIdx.x * 4 + wid;
#pragma unroll
    for (int it = 0; it < 4; ++it) {
        const int n = wg * 4 + it;
        float l = logits[(size_t)n * N_EXP + lane];
        float v1 = l; int i1 = lane;
#pragma unroll
        for (int off = 32; off >= 1; off >>= 1) {
            float ov = __shfl_xor(v1, off);
            int   oi = __shfl_xor(i1, off);
            if (ov > v1 || (ov == v1 && oi < i1)) { v1 = ov; i1 = oi; }
        }
        float l2 = (lane == i1) ? -INFINITY : l;
        float v2 = l2; int i2 = lane;
#pragma unroll
        for (int off = 32; off >= 1; off >>= 1) {
            float ov = __shfl_xor(v2, off);
            int   oi = __shfl_xor(i2, off);
            if (ov > v2 || (ov == v2 && oi < i2)) { v2 = ov; i2 = oi; }
        }
        float Z = expf(l - v1);
#pragma unroll
        for (int off = 32; off >= 1; off >>= 1) Z += __shfl_xor(Z, off);
        if (lane == 0) {
            float p1 = 1.0f / Z;
            float p2 = expf(v2 - v1) / Z;
            float t  = expf(p2 - p1);
            wout[2 * n + 0] = 1.0f / (1.0f + t);
            wout[2 * n + 1] = t / (1.0f + t);
            iout[2 * n + 0] = (float)i1;
            iout[2 * n + 1] = (float)i2;
        }
    }
}

// ---- exact-f32 recompute of flagged tokens ----
__global__ __launch_bounds__(256)
void fixup_kernel(const float* __restrict__ x,
                  const float* __restrict__ W,
                  const float* __restrict__ bias,
                  float* __restrict__ wout,
                  float* __restrict__ iout,
                  const int* __restrict__ counter,
                  const int* __restrict__ list) {
    __shared__ float plds[4][64];
    __shared__ float llds[64];
    int cnt = counter[0];
    if (cnt > N_TOK) cnt = N_TOK;
    const int e = threadIdx.x & 63;
    const int s = threadIdx.x >> 6;
    for (int it = blockIdx.x; it < cnt; it += 128) {
        int n = list[it];
        const float4* xr = (const float4*)(x + (size_t)n * H_DIM) + s * 256;
        const float4* wr = (const float4*)(W + (size_t)e * H_DIM) + s * 256;
        float p = 0.f;
#pragma unroll 8
        for (int j = 0; j < 256; ++j) {
            float4 a = xr[j], w = wr[j];
            p = fmaf(a.x, w.x, p); p = fmaf(a.y, w.y, p);
            p = fmaf(a.z, w.z, p); p = fmaf(a.w, w.w, p);
        }
        plds[s][e] = p;
        __syncthreads();
        if (threadIdx.x < 64)
            llds[e] = ((plds[0][e] + plds[1][e]) + (plds[2][e] + plds[3][e])) + bias[e];
        __syncthreads();
        if (threadIdx.x == 0) {
            float v1 = -INFINITY, v2 = -INFINITY;
            int i1 = 0, i2 = 0;
            for (int i = 0; i < 64; ++i) {
                float li = llds[i];
                if (li > v1)      { v2 = v1; i2 = i1; v1 = li; i1 = i; }
                else if (li > v2) { v2 = li; i2 = i; }
            }
            float Z = 0.0f;
            for (int i = 0; i < 64; ++i) Z += expf(llds[i] - v1);
            float p1 = 1.0f / Z;
            float p2 = expf(v2 - v1) / Z;
            float t  = expf(p2 - p1);
            wout[2 * n + 0] = 1.0f / (1.0f + t);
            wout[2 * n + 1] = t / (1.0f + t);
            iout[2 * n + 0] = (float)i1;
            iout[2 * n + 1] = (float)i2;
        }
        __syncthreads();
    }
}

// ---- expert mask [E][K][N] ----
__global__ __launch_bounds__(256)
void mask_kernel(const float* __restrict__ iout,
                 float* __restrict__ mask) {
    int gid = blockIdx.x * 256 + threadIdx.x;
    int n   = gid & (N_TOK - 1);
    int ek  = gid >> 14;
    float idxf = iout[(size_t)n * 2 + (ek & 1)];
    mask[gid] = (idxf == (float)(ek >> 1)) ? 1.0f : 0.0f;
}

extern "C" void kernel_launch(void* const* d_in, const int* in_sizes, int n_in,
                              void* d_out, int out_size, void* d_ws, size_t ws_size,
                              hipStream_t stream) {
    const float* x  = (const float*)d_in[0];
    const float* W  = (const float*)d_in[1];
    const float* b  = (const float*)d_in[2];

    float* out    = (float*)d_out;
    float* logits = out;
    float* wout   = logits + (size_t)N_TOK * 64;
    float* iout   = wout   + (size_t)N_TOK * 2;
    float* mask   = iout   + (size_t)N_TOK * 2;

    const size_t wsplit = (size_t)N_EXP * H_DIM;                       // 262144
    const size_t need   = 2 * wsplit * sizeof(unsigned short) + 4 + (size_t)N_TOK * 4;
    if (ws_size >= need) {
        unsigned short* wh = (unsigned short*)d_ws;
        unsigned short* wm = wh + wsplit;
        int* counter = (int*)((char*)d_ws + 2 * wsplit * sizeof(unsigned short));
        int* list    = counter + 1;
        wconvert_kernel<<<(int)(wsplit / 256), 256, 0, stream>>>(W, wh, wm, counter);
        router_mfma_kernel<<<N_TOK / BM, 256, 0, stream>>>(x, wh, wm, b, logits,
                                                           wout, iout, counter, list);
        fixup_kernel<<<128, 256, 0, stream>>>(x, W, b, wout, iout, counter, list);
    } else {
        router_logits_f32<<<N_TOK / 32, 256, 0, stream>>>(x, W, b, logits);
        topk_kernel<<<N_TOK / 16, 256, 0, stream>>>(logits, wout, iout);
    }
    mask_kernel<<<(N_EXP * 2 * N_TOK) / 256, 256, 0, stream>>>(iout, mask);
}

// Round 14
// 148.183 us; speedup vs baseline: 1.0299x; 1.0299x over previous
//
#include <hip/hip_runtime.h>
#include <hip/hip_bf16.h>
#include <math.h>

#define H_DIM 4096
#define N_EXP 64
#define N_TOK 16384
#define BM    32
#define KB    64
#define NCHUNK (H_DIM / KB)   // 64
#define MARGIN 1e-3f
#define SLOT_BYTES 24576      // x f32 8 KB @0 | W bf16 16 KB @8192

typedef __attribute__((ext_vector_type(8))) short short8v;
typedef __attribute__((ext_vector_type(4))) float float4v;

__device__ __forceinline__ unsigned short bf16_rn(float f) {
    unsigned u = __builtin_bit_cast(unsigned, f);
    u += 0x7FFFu + ((u >> 16) & 1u);
    return (unsigned short)(u >> 16);
}
__device__ __forceinline__ float bf16_hi_f32(unsigned u) {
    return __builtin_bit_cast(float, u & 0xFFFF0000u);
}
__device__ __forceinline__ void gload_lds16(const void* g, void* l) {
    __builtin_amdgcn_global_load_lds(
        (const __attribute__((address_space(1))) unsigned int*)g,
        (__attribute__((address_space(3))) unsigned int*)l, 16, 0, 0);
}

// ---- W split (2-term): w = wh(trunc) + wm(rn); zero the fixup counter ----
__global__ __launch_bounds__(256)
void wconvert_kernel(const float* __restrict__ W,
                     unsigned short* __restrict__ wh,
                     unsigned short* __restrict__ wm,
                     int* __restrict__ counter) {
    int i = blockIdx.x * 256 + threadIdx.x;
    if (i == 0) *counter = 0;
    float w = W[i];
    unsigned u = __builtin_bit_cast(unsigned, w);
    wh[i] = (unsigned short)(u >> 16);
    wm[i] = bf16_rn(w - bf16_hi_f32(u));
}

// ---- logits: 4-term split-bf16 MFMA; 512 threads / 8 waves per block,
//      16 waves/CU (4 per SIMD); x+W double-buffered LDS; fused topk ----
__global__ __launch_bounds__(512, 4)
void router_mfma_kernel(const float* __restrict__ x,
                        const unsigned short* __restrict__ wh,
                        const unsigned short* __restrict__ wm,
                        const float* __restrict__ bias,
                        float* __restrict__ logits,
                        float* __restrict__ wout,
                        float* __restrict__ iout,
                        int* __restrict__ counter,
                        int* __restrict__ list) {
    __shared__ char smem[2 * SLOT_BYTES];   // 48 KB
    float* olds = (float*)smem;             // [32][66] overlay after K-loop

    const int tid  = threadIdx.x;
    const int lane = tid & 63;
    const int wid  = __builtin_amdgcn_readfirstlane(tid >> 6);  // 0..7
    const int tok0 = blockIdx.x * BM;

    const int q    = lane >> 4;        // 0..3
    const int e15  = lane & 15;
    const int mt   = wid & 1;          // m-tile (16 tokens)
    const int eg   = wid >> 1;         // expert group (16 experts)
    const int arow = mt * 16 + e15;    // token row in x tile
    const int er   = eg * 16 + e15;    // expert row (er&7 == e15&7)

    float4v acc = {0.f, 0.f, 0.f, 0.f};

    auto stage = [&](int slot, int kc) {
        char* base = smem + slot * SLOT_BYTES;
        // x: 512 units (32 rows x 16 u), source pre-swizzled u^(row&15)
        {
            int row = tid >> 4, u = tid & 15;
            int us  = u ^ (row & 15);
            const float* src = x + (size_t)(tok0 + row) * H_DIM + kc + us * 4;
            gload_lds16(src, base + (size_t)(wid * 64) * 16);
        }
        // W: 1024 units (2 terms x 64 e x 8 u), source pre-swizzled u^(e&7)
#pragma unroll
        for (int j = 0; j < 2; ++j) {
            int idx = j * 512 + tid;
            int s = idx >> 9, e = (idx >> 3) & 63, u = idx & 7;
            int us = u ^ (e & 7);
            const unsigned short* wsrc = s ? wm : wh;
            const unsigned short* src  = wsrc + (size_t)e * H_DIM + kc + us * 8;
            gload_lds16(src, base + 8192 + (size_t)(j * 512 + wid * 64) * 16);
        }
    };

    auto compute = [&](int slot) {
        const char* xc = smem + slot * SLOT_BYTES;
        const char* wc = xc + 8192;
#pragma unroll
        for (int t = 0; t < 2; ++t) {
            float f[8];
#pragma unroll
            for (int h = 0; h < 2; ++h) {
                int u = (t * 8 + q * 2 + h) ^ (arow & 15);
                float4 a = *(const float4*)(xc + (size_t)(arow * 16 + u) * 16);
                f[h * 4 + 0] = a.x; f[h * 4 + 1] = a.y;
                f[h * 4 + 2] = a.z; f[h * 4 + 3] = a.w;
            }
            short8v ah, am;
#pragma unroll
            for (int j = 0; j < 8; ++j) {
                unsigned u = __builtin_bit_cast(unsigned, f[j]);
                ah[j] = (short)(u >> 16);
                am[j] = (short)bf16_rn(f[j] - bf16_hi_f32(u));
            }
            int up = (t * 4 + q) ^ (e15 & 7);
            short8v bh = *(const short8v*)(wc + (size_t)(er * 8 + up) * 16);
            short8v bm = *(const short8v*)(wc + 8192 + (size_t)(er * 8 + up) * 16);

            acc = __builtin_amdgcn_mfma_f32_16x16x32_bf16(ah, bh, acc, 0, 0, 0);
            acc = __builtin_amdgcn_mfma_f32_16x16x32_bf16(am, bh, acc, 0, 0, 0);
            acc = __builtin_amdgcn_mfma_f32_16x16x32_bf16(ah, bm, acc, 0, 0, 0);
            acc = __builtin_amdgcn_mfma_f32_16x16x32_bf16(am, bm, acc, 0, 0, 0);
        }
    };

    stage(0, 0);
    for (int c = 0; c < NCHUNK; ++c) {
        __builtin_amdgcn_s_barrier();              // prev compute done -> buf free
        if (c + 1 < NCHUNK) {
            stage((c + 1) & 1, (c + 1) * KB);      // 3 insts/thread
            asm volatile("s_waitcnt vmcnt(3)" ::: "memory");  // chunk c landed
        } else {
            asm volatile("s_waitcnt vmcnt(0)" ::: "memory");
        }
        __builtin_amdgcn_s_barrier();              // all threads see chunk c
        compute(c & 1);
    }
    __syncthreads();                               // free slot 0 for olds overlay

    // ---- epilogue: bias, store logits, stage transpose for fused topk ----
    float bv = bias[er];
#pragma unroll
    for (int r = 0; r < 4; ++r) {
        int trow = mt * 16 + q * 4 + r;            // C: row=(lane>>4)*4+r, col=lane&15
        float v = acc[r] + bv;
        logits[(size_t)(tok0 + trow) * N_EXP + er] = v;
        olds[trow * 66 + er] = v;
    }
    __syncthreads();

    // ---- fused wave-parallel softmax + top-2 (+ near-tie flag) ----
#pragma unroll
    for (int it = 0; it < 4; ++it) {
        const int nl = wid * 4 + it;               // 0..31
        const int n  = tok0 + nl;
        float l = olds[nl * 66 + lane];

        float v1 = l; int i1 = lane;
#pragma unroll
        for (int off = 32; off >= 1; off >>= 1) {
            float ov = __shfl_xor(v1, off);
            int   oi = __shfl_xor(i1, off);
            if (ov > v1 || (ov == v1 && oi < i1)) { v1 = ov; i1 = oi; }
        }
        float l2 = (lane == i1) ? -INFINITY : l;
        float v2 = l2; int i2 = lane;
#pragma unroll
        for (int off = 32; off >= 1; off >>= 1) {
            float ov = __shfl_xor(v2, off);
            int   oi = __shfl_xor(i2, off);
            if (ov > v2 || (ov == v2 && oi < i2)) { v2 = ov; i2 = oi; }
        }
        float l3 = (lane == i1 || lane == i2) ? -INFINITY : l;
        float v3 = l3;
#pragma unroll
        for (int off = 32; off >= 1; off >>= 1)
            v3 = fmaxf(v3, __shfl_xor(v3, off));

        float Z = expf(l - v1);
#pragma unroll
        for (int off = 32; off >= 1; off >>= 1) Z += __shfl_xor(Z, off);

        if (lane == 0) {
            float p1 = 1.0f / Z;
            float p2 = expf(v2 - v1) / Z;
            float t  = expf(p2 - p1);
            wout[2 * n + 0] = 1.0f / (1.0f + t);
            wout[2 * n + 1] = t / (1.0f + t);
            iout[2 * n + 0] = (float)i1;
            iout[2 * n + 1] = (float)i2;
            if ((v1 - v2 < MARGIN) || (v2 - v3 < MARGIN)) {
                int sidx = atomicAdd(counter, 1);
                list[sidx] = n;
            }
        }
    }
}

// ---- fallback exact-f32 GEMM ----
__global__ __launch_bounds__(256)
void router_logits_f32(const float* __restrict__ x,
                       const float* __restrict__ W,
                       const float* __restrict__ bias,
                       float* __restrict__ logits) {
    __shared__ float4 wlds[32 * 64];
    __shared__ float4 xlds[32][32];
    const int tid = threadIdx.x;
    const int lane = tid & 63;
    const int wid = __builtin_amdgcn_readfirstlane(tid >> 6);
    const int tok0b = blockIdx.x * 32;
    const int trow0 = wid * 8;
    float acc[8];
#pragma unroll
    for (int t = 0; t < 8; ++t) acc[t] = 0.0f;
    for (int kc = 0; kc < H_DIM; kc += 128) {
        __syncthreads();
#pragma unroll
        for (int i = 0; i < 8; ++i) {
            int idx = tid + i * 256;
            int se = idx >> 5, sj = idx & 31;
            float4 v = *(const float4*)(W + (size_t)se * H_DIM + kc + sj * 4);
            wlds[sj * 64 + (se ^ (sj & 7))] = v;
        }
#pragma unroll
        for (int i = 0; i < 4; ++i) {
            int idx = tid + i * 256;
            int row = idx >> 5, col = idx & 31;
            xlds[row][col] = *(const float4*)(x + (size_t)(tok0b + row) * H_DIM + kc + col * 4);
        }
        __syncthreads();
#pragma unroll 4
        for (int jg = 0; jg < 32; ++jg) {
            float4 w = wlds[jg * 64 + (lane ^ (jg & 7))];
#pragma unroll
            for (int t = 0; t < 8; ++t) {
                float4 xv = xlds[trow0 + t][jg];
                acc[t] = fmaf(w.x, xv.x, acc[t]);
                acc[t] = fmaf(w.y, xv.y, acc[t]);
                acc[t] = fmaf(w.z, xv.z, acc[t]);
                acc[t] = fmaf(w.w, xv.w, acc[t]);
            }
        }
    }
    float bv = bias[lane];
#pragma unroll
    for (int t = 0; t < 8; ++t)
        logits[(size_t)(tok0b + trow0 + t) * N_EXP + lane] = acc[t] + bv;
}

// ---- standalone wave-parallel topk (fallback path) ----
__global__ __launch_bounds__(256)
void topk_kernel(const float* __restrict__ logits,
                 float* __restrict__ wout,
                 float* __restrict__ iout) {
    const int lane = threadIdx.x & 63;
    const int wid  = threadIdx.x >> 6;
    const int wg   = blockIdx.x * 4 + wid;
#pragma unroll
    for (int it = 0; it < 4; ++it) {
        const int n = wg * 4 + it;
        float l = logits[(size_t)n * N_EXP + lane];
        float v1 = l; int i1 = lane;
#pragma unroll
        for (int off = 32; off >= 1; off >>= 1) {
            float ov = __shfl_xor(v1, off);
            int   oi = __shfl_xor(i1, off);
            if (ov > v1 || (ov == v1 && oi < i1)) { v1 = ov; i1 = oi; }
        }
        float l2 = (lane == i1) ? -INFINITY : l;
        float v2 = l2; int i2 = lane;
#pragma unroll
        for (int off = 32; off >= 1; off >>= 1) {
            float ov = __shfl_xor(v2, off);
            int   oi = __shfl_xor(i2, off);
            if (ov > v2 || (ov == v2 && oi < i2)) { v2 = ov; i2 = oi; }
        }
        float Z = expf(l - v1);
#pragma unroll
        for (int off = 32; off >= 1; off >>= 1) Z += __shfl_xor(Z, off);
        if (lane == 0) {
            float p1 = 1.0f / Z;
            float p2 = expf(v2 - v1) / Z;
            float t  = expf(p2 - p1);
            wout[2 * n + 0] = 1.0f / (1.0f + t);
            wout[2 * n + 1] = t / (1.0f + t);
            iout[2 * n + 0] = (float)i1;
            iout[2 * n + 1] = (float)i2;
        }
    }
}

// ---- exact-f32 recompute of flagged tokens ----
__global__ __launch_bounds__(256)
void fixup_kernel(const float* __restrict__ x,
                  const float* __restrict__ W,
                  const float* __restrict__ bias,
                  float* __restrict__ wout,
                  float* __restrict__ iout,
                  const int* __restrict__ counter,
                  const int* __restrict__ list) {
    __shared__ float plds[4][64];
    __shared__ float llds[64];
    int cnt = counter[0];
    if (cnt > N_TOK) cnt = N_TOK;
    const int e = threadIdx.x & 63;
    const int s = threadIdx.x >> 6;
    for (int it = blockIdx.x; it < cnt; it += 128) {
        int n = list[it];
        const float4* xr = (const float4*)(x + (size_t)n * H_DIM) + s * 256;
        const float4* wr = (const float4*)(W + (size_t)e * H_DIM) + s * 256;
        float p = 0.f;
#pragma unroll 8
        for (int j = 0; j < 256; ++j) {
            float4 a = xr[j], w = wr[j];
            p = fmaf(a.x, w.x, p); p = fmaf(a.y, w.y, p);
            p = fmaf(a.z, w.z, p); p = fmaf(a.w, w.w, p);
        }
        plds[s][e] = p;
        __syncthreads();
        if (threadIdx.x < 64)
            llds[e] = ((plds[0][e] + plds[1][e]) + (plds[2][e] + plds[3][e])) + bias[e];
        __syncthreads();
        if (threadIdx.x == 0) {
            float v1 = -INFINITY, v2 = -INFINITY;
            int i1 = 0, i2 = 0;
            for (int i = 0; i < 64; ++i) {
                float li = llds[i];
                if (li > v1)      { v2 = v1; i2 = i1; v1 = li; i1 = i; }
                else if (li > v2) { v2 = li; i2 = i; }
            }
            float Z = 0.0f;
            for (int i = 0; i < 64; ++i) Z += expf(llds[i] - v1);
            float p1 = 1.0f / Z;
            float p2 = expf(v2 - v1) / Z;
            float t  = expf(p2 - p1);
            wout[2 * n + 0] = 1.0f / (1.0f + t);
            wout[2 * n + 1] = t / (1.0f + t);
            iout[2 * n + 0] = (float)i1;
            iout[2 * n + 1] = (float)i2;
        }
        __syncthreads();
    }
}

// ---- expert mask [E][K][N] ----
__global__ __launch_bounds__(256)
void mask_kernel(const float* __restrict__ iout,
                 float* __restrict__ mask) {
    int gid = blockIdx.x * 256 + threadIdx.x;
    int n   = gid & (N_TOK - 1);
    int ek  = gid >> 14;
    float idxf = iout[(size_t)n * 2 + (ek & 1)];
    mask[gid] = (idxf == (float)(ek >> 1)) ? 1.0f : 0.0f;
}

extern "C" void kernel_launch(void* const* d_in, const int* in_sizes, int n_in,
                              void* d_out, int out_size, void* d_ws, size_t ws_size,
                              hipStream_t stream) {
    const float* x  = (const float*)d_in[0];
    const float* W  = (const float*)d_in[1];
    const float* b  = (const float*)d_in[2];

    float* out    = (float*)d_out;
    float* logits = out;
    float* wout   = logits + (size_t)N_TOK * 64;
    float* iout   = wout   + (size_t)N_TOK * 2;
    float* mask   = iout   + (size_t)N_TOK * 2;

    const size_t wsplit = (size_t)N_EXP * H_DIM;                       // 262144
    const size_t need   = 2 * wsplit * sizeof(unsigned short) + 4 + (size_t)N_TOK * 4;
    if (ws_size >= need) {
        unsigned short* wh = (unsigned short*)d_ws;
        unsigned short* wm = wh + wsplit;
        int* counter = (int*)((char*)d_ws + 2 * wsplit * sizeof(unsigned short));
        int* list    = counter + 1;
        wconvert_kernel<<<(int)(wsplit / 256), 256, 0, stream>>>(W, wh, wm, counter);
        router_mfma_kernel<<<N_TOK / BM, 512, 0, stream>>>(x, wh, wm, b, logits,
                                                           wout, iout, counter, list);
        fixup_kernel<<<128, 256, 0, stream>>>(x, W, b, wout, iout, counter, list);
    } else {
        router_logits_f32<<<N_TOK / 32, 256, 0, stream>>>(x, W, b, logits);
        topk_kernel<<<N_TOK / 16, 256, 0, stream>>>(logits, wout, iout);
    }
    mask_kernel<<<(N_EXP * 2 * N_TOK) / 256, 256, 0, stream>>>(iout, mask);
}